// Round 3
// baseline (12353.892 us; speedup 1.0000x reference)
//
#include <hip/hip_runtime.h>
#include <math.h>

// ---------------- problem constants ----------------
static constexpr int BB = 4;
static constexpr int IMG_H = 512, IMG_W = 1408;
static constexpr int C1 = 32, H1C = 256, W1C = 704;
static constexpr int C2 = 64, H2C = 128, W2C = 352;
static constexpr int C3 = 96, H3C = 64,  W3C = 176;
static constexpr int NPIX = H3C * W3C;          // 11264
static constexpr int KTOP = 200;
static constexpr int BEV = 512;

// ---------------- workspace layout (floats) ----------------
static constexpr size_t SZ_X1   = (size_t)BB * C1 * H1C * W1C;   // 23,068,672
static constexpr size_t SZ_X2   = (size_t)BB * C2 * H2C * W2C;   // 11,534,336
static constexpr size_t SZ_HEAD = (size_t)BB * C3 * H3C * W3C;   //  4,325,376
static constexpr size_t OFF_X1   = 0;
static constexpr size_t OFF_H1   = 0;                 // reuse of x1 (dead after conv2)
static constexpr size_t OFF_D1   = OFF_H1 + SZ_HEAD;
static constexpr size_t OFF_X2   = SZ_X1;
static constexpr size_t OFF_F    = OFF_X2 + SZ_X2;
static constexpr size_t OFF_PROB = OFF_F + SZ_HEAD;
static constexpr size_t OFF_DEP  = OFF_PROB + (size_t)BB * NPIX;
static constexpr size_t OFF_SELS = OFF_DEP + (size_t)BB * NPIX;  // float [BB*KTOP]
static constexpr size_t OFF_SELX = OFF_SELS + (size_t)BB * KTOP; // int
static constexpr size_t OFF_SELY = OFF_SELX + (size_t)BB * KTOP; // int
static constexpr size_t OFF_SELV = OFF_SELY + (size_t)BB * KTOP; // int
static constexpr size_t OFF_BEV  = OFF_SELV + (size_t)BB * KTOP; // float [BB*512*512]

// BN eval scale: 1/sqrt(1 + 1e-5) as in reference (double -> f32)
static constexpr float BN_SCALE = 0.99999500003749973f;

// ---------------- conv 3x3 + BN + ReLU, 1x4 register tile ----------------
template <int CIN, int STRIDE>
__global__ void conv3x3_bnrelu(const float* __restrict__ in, const float* __restrict__ wg,
                               const float* __restrict__ gam, const float* __restrict__ bet,
                               float* __restrict__ out,
                               int OC, int H, int W, int OH, int OW) {
    const int owq = OW >> 2;
    int tid = blockIdx.x * blockDim.x + threadIdx.x;
    int total = BB * OC * OH * owq;
    if (tid >= total) return;
    int oxq = tid % owq; int t = tid / owq;
    int oy  = t % OH;    t /= OH;
    int oc  = t % OC;    int b = t / OC;
    const int ox0 = oxq << 2;
    constexpr int NV = 3 * STRIDE + 3;   // 6 (s1) or 9 (s2)
    float a0 = 0.f, a1 = 0.f, a2 = 0.f, a3 = 0.f;
    const float* wbase = wg + (size_t)oc * CIN * 9;
    const int x0 = ox0 * STRIDE - 1;
    for (int c = 0; c < CIN; ++c) {
        const float* ib = in + (size_t)(b * CIN + c) * H * W;
#pragma unroll
        for (int kh = 0; kh < 3; ++kh) {
            const int iy = oy * STRIDE + kh - 1;
            if (iy < 0 || iy >= H) continue;
            const float* row = ib + (size_t)iy * W;
            float v[NV];
#pragma unroll
            for (int j = 0; j < NV; ++j) {
                const int x = x0 + j;
                v[j] = (x >= 0 && x < W) ? row[x] : 0.0f;
            }
            const float* wr = wbase + (c * 3 + kh) * 3;
#pragma unroll
            for (int kw = 0; kw < 3; ++kw) {
                const float wv = wr[kw];
                a0 = fmaf(v[0 * STRIDE + kw], wv, a0);
                a1 = fmaf(v[1 * STRIDE + kw], wv, a1);
                a2 = fmaf(v[2 * STRIDE + kw], wv, a2);
                a3 = fmaf(v[3 * STRIDE + kw], wv, a3);
            }
        }
    }
    const float s  = gam[oc] * BN_SCALE;
    const float bb = bet[oc];
    float4 o;
    o.x = fmaxf(fmaf(a0, s, bb), 0.0f);
    o.y = fmaxf(fmaf(a1, s, bb), 0.0f);
    o.z = fmaxf(fmaf(a2, s, bb), 0.0f);
    o.w = fmaxf(fmaf(a3, s, bb), 0.0f);
    *reinterpret_cast<float4*>(out + (((size_t)(b * OC + oc) * OH + oy) * OW + ox0)) = o;
}

// ---------------- fused 1x1 heads: hm logits, sigmoid prob, depth ----------------
__global__ void heads_1x1(const float* __restrict__ h1, const float* __restrict__ d1,
                          const float* __restrict__ wh2, const float* __restrict__ bh2,
                          const float* __restrict__ wd2, const float* __restrict__ bd2,
                          float* __restrict__ out_hm, float* __restrict__ out_depth,
                          float* __restrict__ prob, float* __restrict__ depth_ws) {
    int i = blockIdx.x * blockDim.x + threadIdx.x;
    if (i >= BB * NPIX) return;
    int b = i / NPIX, p = i % NPIX;
    const float* hb = h1 + (size_t)b * C3 * NPIX + p;
    const float* db = d1 + (size_t)b * C3 * NPIX + p;
    float hm = 0.f, dl = 0.f;
    for (int c = 0; c < C3; ++c) {
        hm = fmaf(wh2[c], hb[(size_t)c * NPIX], hm);
        dl = fmaf(wd2[c], db[(size_t)c * NPIX], dl);
    }
    hm += bh2[0];
    dl += bd2[0];
    float dep = 1.0f + (1.0f / (1.0f + expf(-dl))) * 79.0f;  // DMIN + sig*(DMAX-DMIN)
    out_hm[i] = hm;
    out_depth[i] = dep;
    prob[i] = 1.0f / (1.0f + expf(-hm));
    depth_ws[i] = dep;
}

// ---------------- exact top-200 (jax.lax.top_k semantics) + unprojection ----------------
__global__ __launch_bounds__(1024) void topk_project(
        const float* __restrict__ prob, const float* __restrict__ depth,
        const float* __restrict__ camP, const float* __restrict__ camT,
        float* __restrict__ selS, int* __restrict__ selX, int* __restrict__ selY,
        int* __restrict__ selV) {
    const int b = blockIdx.x;
    const int tid = threadIdx.x;
    __shared__ float sv[NPIX];
    __shared__ float wrv[16];
    __shared__ int   wri[16];
    __shared__ int   pick[KTOP];
    __shared__ float pscore[KTOP];
    for (int i = tid; i < NPIX; i += 1024) sv[i] = prob[(size_t)b * NPIX + i];
    __syncthreads();
    for (int it = 0; it < KTOP; ++it) {
        float bv = -1.0f; int bi = 0x7fffffff;
        for (int i = tid; i < NPIX; i += 1024) {
            float v = sv[i];
            if (v > bv) { bv = v; bi = i; }   // strictly greater keeps lowest index
        }
#pragma unroll
        for (int off = 32; off; off >>= 1) {
            float ov = __shfl_xor(bv, off, 64);
            int   oi = __shfl_xor(bi, off, 64);
            if (ov > bv || (ov == bv && oi < bi)) { bv = ov; bi = oi; }
        }
        if ((tid & 63) == 0) { wrv[tid >> 6] = bv; wri[tid >> 6] = bi; }
        __syncthreads();
        if (tid == 0) {
            float fv = wrv[0]; int fi = wri[0];
            for (int w = 1; w < 16; ++w)
                if (wrv[w] > fv || (wrv[w] == fv && wri[w] < fi)) { fv = wrv[w]; fi = wri[w]; }
            pick[it] = fi; pscore[it] = fv;
            sv[fi] = -1.0f;
        }
        __syncthreads();
    }
    if (tid < KTOP) {
        const int k = tid;
        const int idx = pick[k];
        const float score = pscore[k];
        const int ys = idx / W3C, xs = idx % W3C;
        const float d = depth[(size_t)b * NPIX + idx];
        const float u = ((float)xs + 0.5f) * 8.0f;   // W/fw = 1408/176
        const float v = ((float)ys + 0.5f) * 8.0f;   // H/fh = 512/64
        const float* P = camP + b * 12;
        const float fx = fmaxf(P[0], 1e-4f), fy = fmaxf(P[5], 1e-4f);
        const float cx = P[2], cy = P[6], tx = P[3], ty = P[7];
        const float x_cam = (u * d - cx * d - tx) / fx;
        const float y_cam = (v * d - cy * d - ty) / fy;
        const float* T = camT + b * 16;
        const float lx = T[0] * x_cam + T[1] * y_cam + T[2] * d + T[3];
        const float ly = T[4] * x_cam + T[5] * y_cam + T[6] * d + T[7];
        const int gx = (int)floorf((lx - (-51.2f)) / 0.2f);
        const int gy = (int)floorf((ly - (-51.2f)) / 0.2f);
        const int valid = (score >= 0.15f) && (gx >= 0) && (gx < BEV) && (gy >= 0) && (gy < BEV);
        selS[b * KTOP + k] = score;
        selX[b * KTOP + k] = gx;
        selY[b * KTOP + k] = gy;
        selV[b * KTOP + k] = valid;
    }
}

// ---------------- BEV zero init ----------------
__global__ void bev_zero(float* __restrict__ bev) {
    int i = blockIdx.x * blockDim.x + threadIdx.x;
    if (i < BB * BEV * BEV) bev[i] = 0.0f;
}

// ---------------- Gaussian max-splat (float-as-int atomicMax; vals >= 0) --------
__global__ void splat(const float* __restrict__ selS, const int* __restrict__ selX,
                      const int* __restrict__ selY, const int* __restrict__ selV,
                      float* __restrict__ bev) {
    int t = blockIdx.x * blockDim.x + threadIdx.x;
    if (t >= BB * KTOP) return;
    int b = t / KTOP;
    if (!selV[t]) return;
    const float score = selS[t];
    const int gx = selX[t], gy = selY[t];
    int* bb = (int*)(bev + (size_t)b * BEV * BEV);
#pragma unroll
    for (int dy = -2; dy <= 2; ++dy) {
        int iy = gy + dy;
        if (iy < 0 || iy >= BEV) continue;
#pragma unroll
        for (int dx = -2; dx <= 2; ++dx) {
            int ix = gx + dx;
            if (ix < 0 || ix >= BEV) continue;
            // gauss = exp(-(dy^2+dx^2)/(2*(5/6)^2)), computed in f32 like jnp
            float g = expf((float)(-(dy * dy + dx * dx)) / 1.3888888888888890f);
            float val = score * g;
            atomicMax(&bb[iy * BEV + ix], __float_as_int(val));
        }
    }
}

// ---------------- clip + logit ----------------
__global__ void bev_finish(const float* __restrict__ bev, float* __restrict__ out_logits,
                           float* __restrict__ out_prob) {
    int i = blockIdx.x * blockDim.x + threadIdx.x;
    if (i >= BB * BEV * BEV) return;
    float p = bev[i];
    p = fminf(fmaxf(p, 1e-4f), 0.9999f);
    out_logits[i] = logf(p) - log1pf(-p);
    out_prob[i] = p;
}

// ---------------- launcher ----------------
extern "C" void kernel_launch(void* const* d_in, const int* in_sizes, int n_in,
                              void* d_out, int out_size, void* d_ws, size_t ws_size,
                              hipStream_t stream) {
    (void)in_sizes; (void)n_in; (void)out_size; (void)ws_size;
    const float* image = (const float*)d_in[0];
    const float* camP  = (const float*)d_in[1];
    const float* camT  = (const float*)d_in[2];
    const float* W1  = (const float*)d_in[3];
    const float* g1  = (const float*)d_in[4];
    const float* b1  = (const float*)d_in[5];
    const float* W2  = (const float*)d_in[6];
    const float* g2  = (const float*)d_in[7];
    const float* b2  = (const float*)d_in[8];
    const float* W3  = (const float*)d_in[9];
    const float* g3  = (const float*)d_in[10];
    const float* b3  = (const float*)d_in[11];
    const float* Wh1 = (const float*)d_in[12];
    const float* gh1 = (const float*)d_in[13];
    const float* bh1 = (const float*)d_in[14];
    const float* Wh2 = (const float*)d_in[15];
    const float* bh2 = (const float*)d_in[16];
    const float* Wd1 = (const float*)d_in[17];
    const float* gd1 = (const float*)d_in[18];
    const float* bd1 = (const float*)d_in[19];
    const float* Wd2 = (const float*)d_in[20];
    const float* bd2 = (const float*)d_in[21];

    float* ws = (float*)d_ws;
    float* x1    = ws + OFF_X1;
    float* x2    = ws + OFF_X2;
    float* feats = ws + OFF_F;
    float* h1    = ws + OFF_H1;
    float* dd1   = ws + OFF_D1;
    float* prob  = ws + OFF_PROB;
    float* depw  = ws + OFF_DEP;
    float* selS  = ws + OFF_SELS;
    int*   selX  = (int*)(ws + OFF_SELX);
    int*   selY  = (int*)(ws + OFF_SELY);
    int*   selV  = (int*)(ws + OFF_SELV);
    float* bev   = ws + OFF_BEV;

    float* out       = (float*)d_out;
    float* out_hm    = out;                    // [4,1,64,176]
    float* out_depth = out + (size_t)BB * NPIX;            // [4,1,64,176]
    float* out_lg    = out + (size_t)2 * BB * NPIX;        // [4,1,512,512]
    float* out_pr    = out_lg + (size_t)BB * BEV * BEV;    // [4,1,512,512]

    const int TPB = 256;
    {   // conv1: 3 -> 32, s2
        int total = BB * C1 * H1C * (W1C / 4);
        conv3x3_bnrelu<3, 2><<<(total + TPB - 1) / TPB, TPB, 0, stream>>>(
            image, W1, g1, b1, x1, C1, IMG_H, IMG_W, H1C, W1C);
    }
    {   // conv2: 32 -> 64, s2
        int total = BB * C2 * H2C * (W2C / 4);
        conv3x3_bnrelu<32, 2><<<(total + TPB - 1) / TPB, TPB, 0, stream>>>(
            x1, W2, g2, b2, x2, C2, H1C, W1C, H2C, W2C);
    }
    {   // conv3: 64 -> 96, s2
        int total = BB * C3 * H3C * (W3C / 4);
        conv3x3_bnrelu<64, 2><<<(total + TPB - 1) / TPB, TPB, 0, stream>>>(
            x2, W3, g3, b3, feats, C3, H2C, W2C, H3C, W3C);
    }
    {   // head convs: 96 -> 96, s1
        int total = BB * C3 * H3C * (W3C / 4);
        conv3x3_bnrelu<96, 1><<<(total + TPB - 1) / TPB, TPB, 0, stream>>>(
            feats, Wh1, gh1, bh1, h1, C3, H3C, W3C, H3C, W3C);
        conv3x3_bnrelu<96, 1><<<(total + TPB - 1) / TPB, TPB, 0, stream>>>(
            feats, Wd1, gd1, bd1, dd1, C3, H3C, W3C, H3C, W3C);
    }
    {   // fused 1x1 heads
        int total = BB * NPIX;
        heads_1x1<<<(total + TPB - 1) / TPB, TPB, 0, stream>>>(
            h1, dd1, Wh2, bh2, Wd2, bd2, out_hm, out_depth, prob, depw);
    }
    // top-k + projection (one block per batch)
    topk_project<<<BB, 1024, 0, stream>>>(prob, depw, camP, camT, selS, selX, selY, selV);
    // BEV
    bev_zero<<<(BB * BEV * BEV + TPB - 1) / TPB, TPB, 0, stream>>>(bev);
    splat<<<(BB * KTOP + TPB - 1) / TPB, TPB, 0, stream>>>(selS, selX, selY, selV, bev);
    bev_finish<<<(BB * BEV * BEV + TPB - 1) / TPB, TPB, 0, stream>>>(bev, out_lg, out_pr);
}

// Round 4
// 1845.810 us; speedup vs baseline: 6.6929x; 6.6929x over previous
//
#include <hip/hip_runtime.h>
#include <math.h>

// ---------------- problem constants ----------------
static constexpr int BB = 4;
static constexpr int IMG_H = 512, IMG_W = 1408;
static constexpr int C1 = 32, H1C = 256, W1C = 704;
static constexpr int C2 = 64, H2C = 128, W2C = 352;
static constexpr int C3 = 96, H3C = 64,  W3C = 176;
static constexpr int NPIX = H3C * W3C;          // 11264
static constexpr int KTOP = 200;
static constexpr int BEV = 512;

// ---------------- workspace layout (floats) ----------------
static constexpr size_t SZ_X1   = (size_t)BB * C1 * H1C * W1C;
static constexpr size_t SZ_X2   = (size_t)BB * C2 * H2C * W2C;
static constexpr size_t SZ_HEAD = (size_t)BB * C3 * H3C * W3C;
static constexpr size_t OFF_X1   = 0;
static constexpr size_t OFF_X2   = SZ_X1;
static constexpr size_t OFF_F    = OFF_X2 + SZ_X2;
static constexpr size_t OFF_PROB = OFF_F + SZ_HEAD;
static constexpr size_t OFF_DEP  = OFF_PROB + (size_t)BB * NPIX;
static constexpr size_t OFF_SELS = OFF_DEP + (size_t)BB * NPIX;  // float [BB*KTOP]
static constexpr size_t OFF_SELX = OFF_SELS + (size_t)BB * KTOP; // int
static constexpr size_t OFF_SELY = OFF_SELX + (size_t)BB * KTOP; // int
static constexpr size_t OFF_SELV = OFF_SELY + (size_t)BB * KTOP; // int
static constexpr size_t OFF_BEV  = OFF_SELV + (size_t)BB * KTOP; // float [BB*512*512]

// BN eval scale: 1/sqrt(1 + 1e-5)
static constexpr float BN_SCALE = 0.99999500003749973f;

// ---------------- tiled conv 3x3 (+BN+ReLU) with LDS input staging ----------------
// Block: 256 threads = 4 waves. Tile: 64 output columns (lane = ox), one output
// row, ALL OC channels (wave w owns channels [w*OC/4, (w+1)*OC/4)).
// Input staged to LDS per CC-channel chunk with coalesced loads; weights read
// via wave-uniform addresses (readfirstlane) -> scalar loads, off the VMEM pipe.
// EPI: 0 = store BN+ReLU conv output.
//      1 = heatmap head: BN+ReLU -> 1x1(w2)+b2 -> store logits (out) + sigmoid (out2)
//      2 = depth head:   BN+ReLU -> 1x1(w2)+b2 -> depth = 1+79*sigmoid -> out and out2
template <int CIN, int STRIDE, int OC, int CC, int EPI>
__global__ __launch_bounds__(256) void conv3x3_tiled(
        const float* __restrict__ in, const float* __restrict__ wg,
        const float* __restrict__ gam, const float* __restrict__ bet,
        float* __restrict__ out,
        const float* __restrict__ w2, const float* __restrict__ b2,
        float* __restrict__ out2,
        int H, int W, int OH, int OW) {
    constexpr int OCW = OC / 4;
    constexpr int SPAN = STRIDE * 64 + 2;     // 130 (s2) / 66 (s1)
    __shared__ float lds[CC][3][SPAN];
    __shared__ float red[4][64];

    const int xt = blockIdx.x, oy = blockIdx.y, b = blockIdx.z;
    const int t = threadIdx.x;
    const int lane = t & 63, wave = t >> 6;
    const int ox0 = xt * 64;
    const int ox = ox0 + lane;
    const int gx0 = ox0 * STRIDE - 1;
    const int li = STRIDE * lane;

    // wave-uniform output-channel base -> scalar weight loads
    const int woc0 = __builtin_amdgcn_readfirstlane(wave) * OCW;
    const float* wbase = wg + (size_t)woc0 * CIN * 9;

    float acc[OCW];
#pragma unroll
    for (int j = 0; j < OCW; ++j) acc[j] = 0.f;

    for (int cin0 = 0; cin0 < CIN; cin0 += CC) {
        __syncthreads();
        // ---- stage CC input channels x 3 rows x SPAN cols (coalesced) ----
        for (int i = t; i < CC * 3 * SPAN; i += 256) {
            const int cc = i / (3 * SPAN);
            const int rem = i % (3 * SPAN);
            const int r = rem / SPAN, x = rem % SPAN;
            const int gx = gx0 + x;
            const int iy = oy * STRIDE + r - 1;
            float v = 0.f;
            if (gx >= 0 && gx < W && iy >= 0 && iy < H)
                v = in[((size_t)(b * CIN + cin0 + cc) * H + iy) * W + gx];
            lds[cc][r][x] = v;
        }
        __syncthreads();
        // ---- compute ----
#pragma unroll 2
        for (int cc = 0; cc < CC; ++cc) {
            const int cin = cin0 + cc;
#pragma unroll
            for (int kh = 0; kh < 3; ++kh) {
                const float v0 = lds[cc][kh][li + 0];
                const float v1 = lds[cc][kh][li + 1];
                const float v2 = lds[cc][kh][li + 2];
                const float* wp = wbase + cin * 9 + kh * 3;
#pragma unroll
                for (int j = 0; j < OCW; ++j) {
                    const float* wj = wp + (size_t)j * CIN * 9;
                    acc[j] = fmaf(v0, wj[0], acc[j]);
                    acc[j] = fmaf(v1, wj[1], acc[j]);
                    acc[j] = fmaf(v2, wj[2], acc[j]);
                }
            }
        }
    }

    const bool lane_ok = (ox < OW);
    if constexpr (EPI == 0) {
#pragma unroll
        for (int j = 0; j < OCW; ++j) {
            const int oc = woc0 + j;
            const float s = gam[oc] * BN_SCALE;
            const float bb = bet[oc];
            const float r = fmaxf(fmaf(acc[j], s, bb), 0.f);
            if (lane_ok)
                out[((size_t)(b * OC + oc) * OH + oy) * OW + ox] = r;
        }
    } else {
        float partial = 0.f;
#pragma unroll
        for (int j = 0; j < OCW; ++j) {
            const int oc = woc0 + j;
            const float s = gam[oc] * BN_SCALE;
            const float bb = bet[oc];
            const float r = fmaxf(fmaf(acc[j], s, bb), 0.f);
            partial = fmaf(r, w2[oc], partial);
        }
        red[wave][lane] = partial;
        __syncthreads();
        if (wave == 0 && lane_ok) {
            const float tot = red[0][lane] + red[1][lane] + red[2][lane] + red[3][lane] + b2[0];
            const size_t pix = (size_t)b * NPIX + (size_t)oy * OW + ox;
            if constexpr (EPI == 1) {
                out[pix] = tot;                               // hm logits
                out2[pix] = 1.0f / (1.0f + expf(-tot));       // prob (ws)
            } else {
                const float dep = 1.0f + (1.0f / (1.0f + expf(-tot))) * 79.0f;
                out[pix] = dep;                               // depth (d_out)
                out2[pix] = dep;                              // depth (ws)
            }
        }
    }
}

// ---------------- exact top-200 (jax.lax.top_k semantics) + unprojection ----------------
__global__ __launch_bounds__(1024) void topk_project(
        const float* __restrict__ prob, const float* __restrict__ depth,
        const float* __restrict__ camP, const float* __restrict__ camT,
        float* __restrict__ selS, int* __restrict__ selX, int* __restrict__ selY,
        int* __restrict__ selV) {
    const int b = blockIdx.x;
    const int tid = threadIdx.x;
    __shared__ float sv[NPIX];
    __shared__ float wrv[16];
    __shared__ int   wri[16];
    __shared__ int   pick[KTOP];
    __shared__ float pscore[KTOP];
    for (int i = tid; i < NPIX; i += 1024) sv[i] = prob[(size_t)b * NPIX + i];
    __syncthreads();
    for (int it = 0; it < KTOP; ++it) {
        float bv = -1.0f; int bi = 0x7fffffff;
        for (int i = tid; i < NPIX; i += 1024) {
            float v = sv[i];
            if (v > bv) { bv = v; bi = i; }   // strictly greater keeps lowest index
        }
#pragma unroll
        for (int off = 32; off; off >>= 1) {
            float ov = __shfl_xor(bv, off, 64);
            int   oi = __shfl_xor(bi, off, 64);
            if (ov > bv || (ov == bv && oi < bi)) { bv = ov; bi = oi; }
        }
        if ((tid & 63) == 0) { wrv[tid >> 6] = bv; wri[tid >> 6] = bi; }
        __syncthreads();
        if (tid == 0) {
            float fv = wrv[0]; int fi = wri[0];
            for (int w = 1; w < 16; ++w)
                if (wrv[w] > fv || (wrv[w] == fv && wri[w] < fi)) { fv = wrv[w]; fi = wri[w]; }
            pick[it] = fi; pscore[it] = fv;
            sv[fi] = -1.0f;
        }
        __syncthreads();
    }
    if (tid < KTOP) {
        const int k = tid;
        const int idx = pick[k];
        const float score = pscore[k];
        const int ys = idx / W3C, xs = idx % W3C;
        const float d = depth[(size_t)b * NPIX + idx];
        const float u = ((float)xs + 0.5f) * 8.0f;   // W/fw = 1408/176
        const float v = ((float)ys + 0.5f) * 8.0f;   // H/fh = 512/64
        const float* P = camP + b * 12;
        const float fx = fmaxf(P[0], 1e-4f), fy = fmaxf(P[5], 1e-4f);
        const float cx = P[2], cy = P[6], tx = P[3], ty = P[7];
        const float x_cam = (u * d - cx * d - tx) / fx;
        const float y_cam = (v * d - cy * d - ty) / fy;
        const float* T = camT + b * 16;
        const float lx = T[0] * x_cam + T[1] * y_cam + T[2] * d + T[3];
        const float ly = T[4] * x_cam + T[5] * y_cam + T[6] * d + T[7];
        const int gx = (int)floorf((lx - (-51.2f)) / 0.2f);
        const int gy = (int)floorf((ly - (-51.2f)) / 0.2f);
        const int valid = (score >= 0.15f) && (gx >= 0) && (gx < BEV) && (gy >= 0) && (gy < BEV);
        selS[b * KTOP + k] = score;
        selX[b * KTOP + k] = gx;
        selY[b * KTOP + k] = gy;
        selV[b * KTOP + k] = valid;
    }
}

// ---------------- BEV zero init ----------------
__global__ void bev_zero(float* __restrict__ bev) {
    int i = blockIdx.x * blockDim.x + threadIdx.x;
    if (i < BB * BEV * BEV) bev[i] = 0.0f;
}

// ---------------- Gaussian max-splat (float-as-int atomicMax; vals >= 0) --------
__global__ void splat(const float* __restrict__ selS, const int* __restrict__ selX,
                      const int* __restrict__ selY, const int* __restrict__ selV,
                      float* __restrict__ bev) {
    int t = blockIdx.x * blockDim.x + threadIdx.x;
    if (t >= BB * KTOP) return;
    int b = t / KTOP;
    if (!selV[t]) return;
    const float score = selS[t];
    const int gx = selX[t], gy = selY[t];
    int* bb = (int*)(bev + (size_t)b * BEV * BEV);
#pragma unroll
    for (int dy = -2; dy <= 2; ++dy) {
        int iy = gy + dy;
        if (iy < 0 || iy >= BEV) continue;
#pragma unroll
        for (int dx = -2; dx <= 2; ++dx) {
            int ix = gx + dx;
            if (ix < 0 || ix >= BEV) continue;
            float g = expf((float)(-(dy * dy + dx * dx)) / 1.3888888888888890f);
            float val = score * g;
            atomicMax(&bb[iy * BEV + ix], __float_as_int(val));
        }
    }
}

// ---------------- clip + logit ----------------
__global__ void bev_finish(const float* __restrict__ bev, float* __restrict__ out_logits,
                           float* __restrict__ out_prob) {
    int i = blockIdx.x * blockDim.x + threadIdx.x;
    if (i >= BB * BEV * BEV) return;
    float p = bev[i];
    p = fminf(fmaxf(p, 1e-4f), 0.9999f);
    out_logits[i] = logf(p) - log1pf(-p);
    out_prob[i] = p;
}

// ---------------- launcher ----------------
extern "C" void kernel_launch(void* const* d_in, const int* in_sizes, int n_in,
                              void* d_out, int out_size, void* d_ws, size_t ws_size,
                              hipStream_t stream) {
    (void)in_sizes; (void)n_in; (void)out_size; (void)ws_size;
    const float* image = (const float*)d_in[0];
    const float* camP  = (const float*)d_in[1];
    const float* camT  = (const float*)d_in[2];
    const float* W1  = (const float*)d_in[3];
    const float* g1  = (const float*)d_in[4];
    const float* b1  = (const float*)d_in[5];
    const float* W2  = (const float*)d_in[6];
    const float* g2  = (const float*)d_in[7];
    const float* b2  = (const float*)d_in[8];
    const float* W3  = (const float*)d_in[9];
    const float* g3  = (const float*)d_in[10];
    const float* b3  = (const float*)d_in[11];
    const float* Wh1 = (const float*)d_in[12];
    const float* gh1 = (const float*)d_in[13];
    const float* bh1 = (const float*)d_in[14];
    const float* Wh2 = (const float*)d_in[15];
    const float* bh2 = (const float*)d_in[16];
    const float* Wd1 = (const float*)d_in[17];
    const float* gd1 = (const float*)d_in[18];
    const float* bd1 = (const float*)d_in[19];
    const float* Wd2 = (const float*)d_in[20];
    const float* bd2 = (const float*)d_in[21];

    float* ws = (float*)d_ws;
    float* x1    = ws + OFF_X1;
    float* x2    = ws + OFF_X2;
    float* feats = ws + OFF_F;
    float* prob  = ws + OFF_PROB;
    float* depw  = ws + OFF_DEP;
    float* selS  = ws + OFF_SELS;
    int*   selX  = (int*)(ws + OFF_SELX);
    int*   selY  = (int*)(ws + OFF_SELY);
    int*   selV  = (int*)(ws + OFF_SELV);
    float* bev   = ws + OFF_BEV;

    float* out       = (float*)d_out;
    float* out_hm    = out;                                // [4,1,64,176]
    float* out_depth = out + (size_t)BB * NPIX;            // [4,1,64,176]
    float* out_lg    = out + (size_t)2 * BB * NPIX;        // [4,1,512,512]
    float* out_pr    = out_lg + (size_t)BB * BEV * BEV;    // [4,1,512,512]

    // conv1: 3 -> 32, s2, out 256x704 (704 = 11*64)
    conv3x3_tiled<3, 2, 32, 3, 0><<<dim3(11, H1C, BB), 256, 0, stream>>>(
        image, W1, g1, b1, x1, nullptr, nullptr, nullptr, IMG_H, IMG_W, H1C, W1C);
    // conv2: 32 -> 64, s2, out 128x352 (6 tiles, last partial)
    conv3x3_tiled<32, 2, 64, 8, 0><<<dim3(6, H2C, BB), 256, 0, stream>>>(
        x1, W2, g2, b2, x2, nullptr, nullptr, nullptr, H1C, W1C, H2C, W2C);
    // conv3: 64 -> 96, s2, out 64x176 (3 tiles, last partial)
    conv3x3_tiled<64, 2, 96, 8, 0><<<dim3(3, H3C, BB), 256, 0, stream>>>(
        x2, W3, g3, b3, feats, nullptr, nullptr, nullptr, H2C, W2C, H3C, W3C);
    // heatmap head: 96 -> 96 (s1) -> 1x1 -> hm logits + prob
    conv3x3_tiled<96, 1, 96, 8, 1><<<dim3(3, H3C, BB), 256, 0, stream>>>(
        feats, Wh1, gh1, bh1, out_hm, Wh2, bh2, prob, H3C, W3C, H3C, W3C);
    // depth head: 96 -> 96 (s1) -> 1x1 -> depth (out + ws)
    conv3x3_tiled<96, 1, 96, 8, 2><<<dim3(3, H3C, BB), 256, 0, stream>>>(
        feats, Wd1, gd1, bd1, out_depth, Wd2, bd2, depw, H3C, W3C, H3C, W3C);

    // top-k + projection (one block per batch)
    topk_project<<<BB, 1024, 0, stream>>>(prob, depw, camP, camT, selS, selX, selY, selV);
    // BEV
    const int TPB = 256;
    bev_zero<<<(BB * BEV * BEV + TPB - 1) / TPB, TPB, 0, stream>>>(bev);
    splat<<<(BB * KTOP + TPB - 1) / TPB, TPB, 0, stream>>>(selS, selX, selY, selV, bev);
    bev_finish<<<(BB * BEV * BEV + TPB - 1) / TPB, TPB, 0, stream>>>(bev, out_lg, out_pr);
}

// Round 5
// 1379.798 us; speedup vs baseline: 8.9534x; 1.3377x over previous
//
#include <hip/hip_runtime.h>
#include <math.h>

// ---------------- problem constants ----------------
static constexpr int BB = 4;
static constexpr int IMG_H = 512, IMG_W = 1408;
static constexpr int C1 = 32, H1C = 256, W1C = 704;
static constexpr int C2 = 64, H2C = 128, W2C = 352;
static constexpr int C3 = 96, H3C = 64,  W3C = 176;
static constexpr int NPIX = H3C * W3C;          // 11264
static constexpr int KTOP = 200;
static constexpr int BEV = 512;

// ---------------- workspace layout (floats) ----------------
static constexpr size_t SZ_X1   = (size_t)BB * C1 * H1C * W1C;
static constexpr size_t SZ_X2   = (size_t)BB * C2 * H2C * W2C;
static constexpr size_t SZ_HEAD = (size_t)BB * C3 * H3C * W3C;
static constexpr size_t OFF_X1   = 0;
static constexpr size_t OFF_X2   = SZ_X1;
static constexpr size_t OFF_F    = OFF_X2 + SZ_X2;
static constexpr size_t OFF_PROB = OFF_F + SZ_HEAD;
static constexpr size_t OFF_DEP  = OFF_PROB + (size_t)BB * NPIX;
static constexpr size_t OFF_BEV  = OFF_DEP + (size_t)BB * NPIX;  // float [BB*512*512]

// BN eval scale: 1/sqrt(1 + 1e-5)
static constexpr float BN_SCALE = 0.99999500003749973f;

// ---------------- tiled conv 3x3 (+BN+ReLU) with LDS input staging ----------------
// (unchanged from the passing Round-4 kernel)
template <int CIN, int STRIDE, int OC, int CC, int EPI>
__global__ __launch_bounds__(256) void conv3x3_tiled(
        const float* __restrict__ in, const float* __restrict__ wg,
        const float* __restrict__ gam, const float* __restrict__ bet,
        float* __restrict__ out,
        const float* __restrict__ w2, const float* __restrict__ b2,
        float* __restrict__ out2,
        int H, int W, int OH, int OW) {
    constexpr int OCW = OC / 4;
    constexpr int SPAN = STRIDE * 64 + 2;     // 130 (s2) / 66 (s1)
    __shared__ float lds[CC][3][SPAN];
    __shared__ float red[4][64];

    const int xt = blockIdx.x, oy = blockIdx.y, b = blockIdx.z;
    const int t = threadIdx.x;
    const int lane = t & 63, wave = t >> 6;
    const int ox0 = xt * 64;
    const int ox = ox0 + lane;
    const int gx0 = ox0 * STRIDE - 1;
    const int li = STRIDE * lane;

    const int woc0 = __builtin_amdgcn_readfirstlane(wave) * OCW;
    const float* wbase = wg + (size_t)woc0 * CIN * 9;

    float acc[OCW];
#pragma unroll
    for (int j = 0; j < OCW; ++j) acc[j] = 0.f;

    for (int cin0 = 0; cin0 < CIN; cin0 += CC) {
        __syncthreads();
        for (int i = t; i < CC * 3 * SPAN; i += 256) {
            const int cc = i / (3 * SPAN);
            const int rem = i % (3 * SPAN);
            const int r = rem / SPAN, x = rem % SPAN;
            const int gx = gx0 + x;
            const int iy = oy * STRIDE + r - 1;
            float v = 0.f;
            if (gx >= 0 && gx < W && iy >= 0 && iy < H)
                v = in[((size_t)(b * CIN + cin0 + cc) * H + iy) * W + gx];
            lds[cc][r][x] = v;
        }
        __syncthreads();
#pragma unroll 2
        for (int cc = 0; cc < CC; ++cc) {
            const int cin = cin0 + cc;
#pragma unroll
            for (int kh = 0; kh < 3; ++kh) {
                const float v0 = lds[cc][kh][li + 0];
                const float v1 = lds[cc][kh][li + 1];
                const float v2 = lds[cc][kh][li + 2];
                const float* wp = wbase + cin * 9 + kh * 3;
#pragma unroll
                for (int j = 0; j < OCW; ++j) {
                    const float* wj = wp + (size_t)j * CIN * 9;
                    acc[j] = fmaf(v0, wj[0], acc[j]);
                    acc[j] = fmaf(v1, wj[1], acc[j]);
                    acc[j] = fmaf(v2, wj[2], acc[j]);
                }
            }
        }
    }

    const bool lane_ok = (ox < OW);
    if constexpr (EPI == 0) {
#pragma unroll
        for (int j = 0; j < OCW; ++j) {
            const int oc = woc0 + j;
            const float s = gam[oc] * BN_SCALE;
            const float bb = bet[oc];
            const float r = fmaxf(fmaf(acc[j], s, bb), 0.f);
            if (lane_ok)
                out[((size_t)(b * OC + oc) * OH + oy) * OW + ox] = r;
        }
    } else {
        float partial = 0.f;
#pragma unroll
        for (int j = 0; j < OCW; ++j) {
            const int oc = woc0 + j;
            const float s = gam[oc] * BN_SCALE;
            const float bb = bet[oc];
            const float r = fmaxf(fmaf(acc[j], s, bb), 0.f);
            partial = fmaf(r, w2[oc], partial);
        }
        red[wave][lane] = partial;
        __syncthreads();
        if (wave == 0 && lane_ok) {
            const float tot = red[0][lane] + red[1][lane] + red[2][lane] + red[3][lane] + b2[0];
            const size_t pix = (size_t)b * NPIX + (size_t)oy * OW + ox;
            if constexpr (EPI == 1) {
                out[pix] = tot;                               // hm logits
                out2[pix] = 1.0f / (1.0f + expf(-tot));       // prob (ws)
            } else {
                const float dep = 1.0f + (1.0f / (1.0f + expf(-tot))) * 79.0f;
                out[pix] = dep;                               // depth (d_out)
                out2[pix] = dep;                              // depth (ws)
            }
        }
    }
}

// ---------------- select top-K SET by value-bisection + fused projection/splat ----
// Key fact: bev output depends only on the SET of (score, gx, gy) splatted
// (max-combine is order-independent). That set = top-200-by-prob entries with
// score >= 0.15 (jax tie-break: lowest index first on the boundary value).
// prob >= 0 -> float order == uint bit order -> bisect the bit pattern.
__global__ __launch_bounds__(1024) void select_splat(
        const float* __restrict__ prob, const float* __restrict__ depth,
        const float* __restrict__ camP, const float* __restrict__ camT,
        float* __restrict__ bev) {
    const int b = blockIdx.x;
    const int tid = threadIdx.x;
    const int lane = tid & 63, wave = tid >> 6;
    __shared__ unsigned sv[NPIX];
    __shared__ unsigned wcnt[16];
    __shared__ unsigned scan_w[16];
    __shared__ unsigned bcast;
    __shared__ int list[KTOP];
    __shared__ int nsel;

    for (int i = tid; i < NPIX; i += 1024) sv[i] = __float_as_uint(prob[(size_t)b * NPIX + i]);
    if (tid == 0) nsel = 0;
    __syncthreads();

    // uniform block-wide count of {bits >= t}; every thread returns the total
    auto countGE = [&](unsigned t) -> unsigned {
        unsigned c = 0;
        for (int i = tid; i < NPIX; i += 1024) c += (sv[i] >= t) ? 1u : 0u;
#pragma unroll
        for (int off = 32; off; off >>= 1) c += __shfl_xor((int)c, off, 64);
        if (lane == 0) wcnt[wave] = c;
        __syncthreads();
        if (tid == 0) {
            unsigned tot = 0;
            for (int w = 0; w < 16; ++w) tot += wcnt[w];
            bcast = tot;
        }
        __syncthreads();
        unsigned tot = bcast;
        __syncthreads();
        return tot;
    };

    const unsigned THRB = 0x3E19999Au;          // __float_as_uint(0.15f)
    unsigned tstrict;                            // select all bits > tstrict
    unsigned need = 0;                           // extra ties (== tstrict) wanted, by index order
    const unsigned c_thr = countGE(THRB);
    if (c_thr <= (unsigned)KTOP) {
        tstrict = THRB - 1u;                     // take all >= 0.15
    } else {
        unsigned lo = THRB, hi = 0x3F800000u;    // search kth value in [0.15, 1.0]
        while (lo < hi) {                        // uniform loop: lo/hi identical per thread
            unsigned mid = lo + (hi - lo + 1u) / 2u;
            unsigned c = countGE(mid);
            if (c >= (unsigned)KTOP) lo = mid; else hi = mid - 1u;
        }
        tstrict = lo;                            // kth-largest value; cnt(>lo) < K <= cnt(>=lo)
        need = (unsigned)KTOP - countGE(lo + 1u);
    }

    // pass A: append all strictly-greater entries (order irrelevant)
    for (int i = tid; i < NPIX; i += 1024)
        if (sv[i] > tstrict) { int p = atomicAdd(&nsel, 1); list[p] = i; }
    __syncthreads();

    // pass B: boundary ties, first `need` by increasing index (block-ordered scan)
    if (need > 0) {
        const unsigned tv = tstrict;
        const int CH = NPIX / 1024;              // 11, exact
        const int i0 = tid * CH, i1 = i0 + CH;
        unsigned cnt = 0;
        for (int i = i0; i < i1; ++i) cnt += (sv[i] == tv) ? 1u : 0u;
        unsigned inc = cnt;
#pragma unroll
        for (int off = 1; off < 64; off <<= 1) {
            unsigned o = __shfl_up((int)inc, off, 64);
            if (lane >= off) inc += o;
        }
        if (lane == 63) scan_w[wave] = inc;
        __syncthreads();
        if (tid == 0) {
            unsigned s = 0;
            for (int w = 0; w < 16; ++w) { unsigned x = scan_w[w]; scan_w[w] = s; s += x; }
        }
        __syncthreads();
        unsigned r = inc - cnt + scan_w[wave];   // exclusive global rank of first tie in chunk
        for (int i = i0; i < i1; ++i) {
            if (sv[i] == tv) {
                if (r < need) { int p = atomicAdd(&nsel, 1); list[p] = i; }
                ++r;
            }
        }
        __syncthreads();
    }

    // pass C: projection + Gaussian max-splat for the selected set
    const int ns = nsel;
    if (tid < ns) {
        const int idx = list[tid];
        const float score = __uint_as_float(sv[idx]);
        const int ys = idx / W3C, xs = idx % W3C;
        const float d = depth[(size_t)b * NPIX + idx];
        const float u = ((float)xs + 0.5f) * 8.0f;   // W/fw
        const float v = ((float)ys + 0.5f) * 8.0f;   // H/fh
        const float* P = camP + b * 12;
        const float fx = fmaxf(P[0], 1e-4f), fy = fmaxf(P[5], 1e-4f);
        const float cx = P[2], cy = P[6], tx = P[3], ty = P[7];
        const float x_cam = (u * d - cx * d - tx) / fx;
        const float y_cam = (v * d - cy * d - ty) / fy;
        const float* T = camT + b * 16;
        const float lx = T[0] * x_cam + T[1] * y_cam + T[2] * d + T[3];
        const float ly = T[4] * x_cam + T[5] * y_cam + T[6] * d + T[7];
        const int gx = (int)floorf((lx - (-51.2f)) / 0.2f);
        const int gy = (int)floorf((ly - (-51.2f)) / 0.2f);
        if (gx >= 0 && gx < BEV && gy >= 0 && gy < BEV) {   // score>=0.15 guaranteed
            int* bb = (int*)(bev + (size_t)b * BEV * BEV);
#pragma unroll
            for (int dy = -2; dy <= 2; ++dy) {
                const int iy = gy + dy;
                if (iy < 0 || iy >= BEV) continue;
#pragma unroll
                for (int dx = -2; dx <= 2; ++dx) {
                    const int ix = gx + dx;
                    if (ix < 0 || ix >= BEV) continue;
                    const float g = expf((float)(-(dy * dy + dx * dx)) / 1.3888888888888890f);
                    atomicMax(&bb[iy * BEV + ix], __float_as_int(score * g));
                }
            }
        }
    }
}

// ---------------- BEV zero init ----------------
__global__ void bev_zero(float* __restrict__ bev) {
    int i = blockIdx.x * blockDim.x + threadIdx.x;
    if (i < BB * BEV * BEV) bev[i] = 0.0f;
}

// ---------------- clip + logit ----------------
__global__ void bev_finish(const float* __restrict__ bev, float* __restrict__ out_logits,
                           float* __restrict__ out_prob) {
    int i = blockIdx.x * blockDim.x + threadIdx.x;
    if (i >= BB * BEV * BEV) return;
    float p = bev[i];
    p = fminf(fmaxf(p, 1e-4f), 0.9999f);
    out_logits[i] = logf(p) - log1pf(-p);
    out_prob[i] = p;
}

// ---------------- launcher ----------------
extern "C" void kernel_launch(void* const* d_in, const int* in_sizes, int n_in,
                              void* d_out, int out_size, void* d_ws, size_t ws_size,
                              hipStream_t stream) {
    (void)in_sizes; (void)n_in; (void)out_size; (void)ws_size;
    const float* image = (const float*)d_in[0];
    const float* camP  = (const float*)d_in[1];
    const float* camT  = (const float*)d_in[2];
    const float* W1  = (const float*)d_in[3];
    const float* g1  = (const float*)d_in[4];
    const float* b1  = (const float*)d_in[5];
    const float* W2  = (const float*)d_in[6];
    const float* g2  = (const float*)d_in[7];
    const float* b2  = (const float*)d_in[8];
    const float* W3  = (const float*)d_in[9];
    const float* g3  = (const float*)d_in[10];
    const float* b3  = (const float*)d_in[11];
    const float* Wh1 = (const float*)d_in[12];
    const float* gh1 = (const float*)d_in[13];
    const float* bh1 = (const float*)d_in[14];
    const float* Wh2 = (const float*)d_in[15];
    const float* bh2 = (const float*)d_in[16];
    const float* Wd1 = (const float*)d_in[17];
    const float* gd1 = (const float*)d_in[18];
    const float* bd1 = (const float*)d_in[19];
    const float* Wd2 = (const float*)d_in[20];
    const float* bd2 = (const float*)d_in[21];

    float* ws = (float*)d_ws;
    float* x1    = ws + OFF_X1;
    float* x2    = ws + OFF_X2;
    float* feats = ws + OFF_F;
    float* prob  = ws + OFF_PROB;
    float* depw  = ws + OFF_DEP;
    float* bev   = ws + OFF_BEV;

    float* out       = (float*)d_out;
    float* out_hm    = out;                                // [4,1,64,176]
    float* out_depth = out + (size_t)BB * NPIX;            // [4,1,64,176]
    float* out_lg    = out + (size_t)2 * BB * NPIX;        // [4,1,512,512]
    float* out_pr    = out_lg + (size_t)BB * BEV * BEV;    // [4,1,512,512]

    // conv1: 3 -> 32, s2
    conv3x3_tiled<3, 2, 32, 3, 0><<<dim3(11, H1C, BB), 256, 0, stream>>>(
        image, W1, g1, b1, x1, nullptr, nullptr, nullptr, IMG_H, IMG_W, H1C, W1C);
    // conv2: 32 -> 64, s2
    conv3x3_tiled<32, 2, 64, 8, 0><<<dim3(6, H2C, BB), 256, 0, stream>>>(
        x1, W2, g2, b2, x2, nullptr, nullptr, nullptr, H1C, W1C, H2C, W2C);
    // conv3: 64 -> 96, s2
    conv3x3_tiled<64, 2, 96, 8, 0><<<dim3(3, H3C, BB), 256, 0, stream>>>(
        x2, W3, g3, b3, feats, nullptr, nullptr, nullptr, H2C, W2C, H3C, W3C);
    // heatmap head: 96 -> 96 (s1) -> 1x1 -> hm logits + prob
    conv3x3_tiled<96, 1, 96, 8, 1><<<dim3(3, H3C, BB), 256, 0, stream>>>(
        feats, Wh1, gh1, bh1, out_hm, Wh2, bh2, prob, H3C, W3C, H3C, W3C);
    // depth head: 96 -> 96 (s1) -> 1x1 -> depth (out + ws)
    conv3x3_tiled<96, 1, 96, 8, 2><<<dim3(3, H3C, BB), 256, 0, stream>>>(
        feats, Wd1, gd1, bd1, out_depth, Wd2, bd2, depw, H3C, W3C, H3C, W3C);

    // BEV: zero -> select+splat -> finish
    const int TPB = 256;
    bev_zero<<<(BB * BEV * BEV + TPB - 1) / TPB, TPB, 0, stream>>>(bev);
    select_splat<<<BB, 1024, 0, stream>>>(prob, depw, camP, camT, bev);
    bev_finish<<<(BB * BEV * BEV + TPB - 1) / TPB, TPB, 0, stream>>>(bev, out_lg, out_pr);
}

// Round 10
// 938.928 us; speedup vs baseline: 13.1574x; 1.4695x over previous
//
#include <hip/hip_runtime.h>
#include <math.h>

// ---------------- problem constants ----------------
static constexpr int BB = 4;
static constexpr int IMG_H = 512, IMG_W = 1408;
static constexpr int C1 = 32, H1C = 256, W1C = 704;
static constexpr int C2 = 64, H2C = 128, W2C = 352;
static constexpr int C3 = 96, H3C = 64,  W3C = 176;
static constexpr int NPIX = H3C * W3C;          // 11264
static constexpr int KTOP = 200;
static constexpr int BEV = 512;

// ---------------- workspace layout (floats) ----------------
static constexpr size_t SZ_X1   = (size_t)BB * C1 * H1C * W1C;
static constexpr size_t SZ_X2   = (size_t)BB * C2 * H2C * W2C;
static constexpr size_t SZ_HEAD = (size_t)BB * C3 * H3C * W3C;
static constexpr size_t OFF_X1   = 0;
static constexpr size_t OFF_X2   = SZ_X1;
static constexpr size_t OFF_F    = OFF_X2 + SZ_X2;
static constexpr size_t OFF_PROB = OFF_F + SZ_HEAD;
static constexpr size_t OFF_DEP  = OFF_PROB + (size_t)BB * NPIX;
static constexpr size_t OFF_HMA  = OFF_DEP + (size_t)BB * NPIX;   // hm-logit accum
static constexpr size_t OFF_DLA  = OFF_HMA + (size_t)BB * NPIX;   // depth-logit accum
static constexpr size_t OFF_BEV  = OFF_DLA + (size_t)BB * NPIX;   // float [BB*512*512]

// BN eval scale: 1/sqrt(1 + 1e-5)
static constexpr float BN_SCALE = 0.99999500003749973f;

// ---------------- tiled conv 3x3 (+BN+ReLU) with double-buffered LDS staging ----
// Block: 256 threads = 4 waves, 64 output columns (lane = ox), one output row.
// OCG splits the OC dimension across OCG blocks (wave of block g owns
// (4g+wave)*OCW .. +OCW channels). Staging is reg-issued early (T14) and
// committed to the alternate LDS buffer after compute -> 1 barrier/chunk and
// global latency hides under FMAs.
// EPI: 0 = store BN+ReLU conv output.
//      1 = BN+ReLU -> dot with w2 over this block's channels -> atomicAdd(out)
//          (out must be zero-initialized; 2 commutative f32 adds = deterministic)
template <int CIN, int STRIDE, int OC, int CC, int EPI, int OCG>
__global__ __launch_bounds__(256) void conv3x3_tiled(
        const float* __restrict__ in, const float* __restrict__ wg,
        const float* __restrict__ gam, const float* __restrict__ bet,
        float* __restrict__ out, const float* __restrict__ w2,
        int H, int W, int OH, int OW) {
    constexpr int OCW = OC / (4 * OCG);
    constexpr int SPAN = STRIDE * 64 + 2;     // 130 (s2) / 66 (s1)
    constexpr int ELEMS = CC * 3 * SPAN;
    constexpr int NLD = (ELEMS + 255) / 256;
    constexpr int NCH = CIN / CC;
    __shared__ float lds[2][ELEMS];
    __shared__ float red[4][64];

    const int xt = blockIdx.x / OCG, g = blockIdx.x % OCG;
    const int oy = blockIdx.y, b = blockIdx.z;
    const int t = threadIdx.x;
    const int lane = t & 63, wave = t >> 6;
    const int ox0 = xt * 64;
    const int ox = ox0 + lane;
    const int gx0 = ox0 * STRIDE - 1;
    const int li = STRIDE * lane;

    const int woc0 = (__builtin_amdgcn_readfirstlane(wave) + 4 * g) * OCW;
    const float* wbase = wg + (size_t)woc0 * CIN * 9;

    float acc[OCW];
#pragma unroll
    for (int j = 0; j < OCW; ++j) acc[j] = 0.f;

    float st[NLD];
    auto issue = [&](int cin0) {
#pragma unroll
        for (int l = 0; l < NLD; ++l) {
            const int i = t + l * 256;
            float v = 0.f;
            if (i < ELEMS) {
                const int cc = i / (3 * SPAN);
                const int rem = i % (3 * SPAN);
                const int r = rem / SPAN, x = rem % SPAN;
                const int gx = gx0 + x;
                const int iy = oy * STRIDE + r - 1;
                if (gx >= 0 && gx < W && iy >= 0 && iy < H)
                    v = in[((size_t)(b * CIN + cin0 + cc) * H + iy) * W + gx];
            }
            st[l] = v;
        }
    };
    auto commit = [&](int buf) {
#pragma unroll
        for (int l = 0; l < NLD; ++l) {
            const int i = t + l * 256;
            if (i < ELEMS) lds[buf][i] = st[l];
        }
    };

    issue(0);
    commit(0);
    __syncthreads();
    for (int k = 0; k < NCH; ++k) {
        const int cur = k & 1;
        if (k + 1 < NCH) issue((k + 1) * CC);
        const float* __restrict__ L = lds[cur];
#pragma unroll 2
        for (int cc = 0; cc < CC; ++cc) {
            const int cin = k * CC + cc;
#pragma unroll
            for (int kh = 0; kh < 3; ++kh) {
                const float v0 = L[(cc * 3 + kh) * SPAN + li + 0];
                const float v1 = L[(cc * 3 + kh) * SPAN + li + 1];
                const float v2 = L[(cc * 3 + kh) * SPAN + li + 2];
                const float* wp = wbase + cin * 9 + kh * 3;
#pragma unroll
                for (int j = 0; j < OCW; ++j) {
                    const float* wj = wp + (size_t)j * CIN * 9;
                    acc[j] = fmaf(v0, wj[0], acc[j]);
                    acc[j] = fmaf(v1, wj[1], acc[j]);
                    acc[j] = fmaf(v2, wj[2], acc[j]);
                }
            }
        }
        if (k + 1 < NCH) commit((k + 1) & 1);
        __syncthreads();
    }

    const bool lane_ok = (ox < OW);
    if constexpr (EPI == 0) {
#pragma unroll
        for (int j = 0; j < OCW; ++j) {
            const int oc = woc0 + j;
            const float s = gam[oc] * BN_SCALE;
            const float bb = bet[oc];
            const float r = fmaxf(fmaf(acc[j], s, bb), 0.f);
            if (lane_ok)
                out[((size_t)(b * OC + oc) * OH + oy) * OW + ox] = r;
        }
    } else {
        float partial = 0.f;
#pragma unroll
        for (int j = 0; j < OCW; ++j) {
            const int oc = woc0 + j;
            const float s = gam[oc] * BN_SCALE;
            const float bb = bet[oc];
            const float r = fmaxf(fmaf(acc[j], s, bb), 0.f);
            partial = fmaf(r, w2[oc], partial);
        }
        red[wave][lane] = partial;
        __syncthreads();
        if (wave == 0 && lane_ok) {
            const float s = red[0][lane] + red[1][lane] + red[2][lane] + red[3][lane];
            atomicAdd(&out[(size_t)b * NPIX + (size_t)oy * OW + ox], s);
        }
    }
}

// ---------------- zero init: bev + head accumulators ----------------
__global__ void zero_init(float* __restrict__ bev, float* __restrict__ hma,
                          float* __restrict__ dla) {
    int i = blockIdx.x * blockDim.x + threadIdx.x;
    if (i < BB * BEV * BEV) bev[i] = 0.0f;
    if (i < BB * NPIX) { hma[i] = 0.0f; dla[i] = 0.0f; }
}

// ---------------- head finish: bias + sigmoid / depth transform ----------------
__global__ void heads_finish(const float* __restrict__ hma, const float* __restrict__ dla,
                             const float* __restrict__ bh2, const float* __restrict__ bd2,
                             float* __restrict__ out_hm, float* __restrict__ out_depth,
                             float* __restrict__ prob, float* __restrict__ depw) {
    int i = blockIdx.x * blockDim.x + threadIdx.x;
    if (i >= BB * NPIX) return;
    const float hm = hma[i] + bh2[0];
    out_hm[i] = hm;
    prob[i] = 1.0f / (1.0f + expf(-hm));
    const float dl = dla[i] + bd2[0];
    const float dep = 1.0f + (1.0f / (1.0f + expf(-dl))) * 79.0f;
    out_depth[i] = dep;
    depw[i] = dep;
}

// ---------------- select top-K SET by value-bisection + fused projection/splat ----
__global__ __launch_bounds__(1024) void select_splat(
        const float* __restrict__ prob, const float* __restrict__ depth,
        const float* __restrict__ camP, const float* __restrict__ camT,
        float* __restrict__ bev) {
    const int b = blockIdx.x;
    const int tid = threadIdx.x;
    const int lane = tid & 63, wave = tid >> 6;
    __shared__ unsigned sv[NPIX];
    __shared__ unsigned wcnt[16];
    __shared__ unsigned scan_w[16];
    __shared__ unsigned bcast;
    __shared__ int list[KTOP];
    __shared__ int nsel;

    for (int i = tid; i < NPIX; i += 1024) sv[i] = __float_as_uint(prob[(size_t)b * NPIX + i]);
    if (tid == 0) nsel = 0;
    __syncthreads();

    auto countGE = [&](unsigned t) -> unsigned {
        unsigned c = 0;
        for (int i = tid; i < NPIX; i += 1024) c += (sv[i] >= t) ? 1u : 0u;
#pragma unroll
        for (int off = 32; off; off >>= 1) c += __shfl_xor((int)c, off, 64);
        if (lane == 0) wcnt[wave] = c;
        __syncthreads();
        if (tid == 0) {
            unsigned tot = 0;
            for (int w = 0; w < 16; ++w) tot += wcnt[w];
            bcast = tot;
        }
        __syncthreads();
        unsigned tot = bcast;
        __syncthreads();
        return tot;
    };

    const unsigned THRB = 0x3E19999Au;          // __float_as_uint(0.15f)
    unsigned tstrict;
    unsigned need = 0;
    const unsigned c_thr = countGE(THRB);
    if (c_thr <= (unsigned)KTOP) {
        tstrict = THRB - 1u;
    } else {
        unsigned lo = THRB, hi = 0x3F800000u;
        while (lo < hi) {
            unsigned mid = lo + (hi - lo + 1u) / 2u;
            unsigned c = countGE(mid);
            if (c >= (unsigned)KTOP) lo = mid; else hi = mid - 1u;
        }
        tstrict = lo;
        need = (unsigned)KTOP - countGE(lo + 1u);
    }

    for (int i = tid; i < NPIX; i += 1024)
        if (sv[i] > tstrict) { int p = atomicAdd(&nsel, 1); list[p] = i; }
    __syncthreads();

    if (need > 0) {
        const unsigned tv = tstrict;
        const int CH = NPIX / 1024;
        const int i0 = tid * CH, i1 = i0 + CH;
        unsigned cnt = 0;
        for (int i = i0; i < i1; ++i) cnt += (sv[i] == tv) ? 1u : 0u;
        unsigned inc = cnt;
#pragma unroll
        for (int off = 1; off < 64; off <<= 1) {
            unsigned o = __shfl_up((int)inc, off, 64);
            if (lane >= off) inc += o;
        }
        if (lane == 63) scan_w[wave] = inc;
        __syncthreads();
        if (tid == 0) {
            unsigned s = 0;
            for (int w = 0; w < 16; ++w) { unsigned x = scan_w[w]; scan_w[w] = s; s += x; }
        }
        __syncthreads();
        unsigned r = inc - cnt + scan_w[wave];
        for (int i = i0; i < i1; ++i) {
            if (sv[i] == tv) {
                if (r < need) { int p = atomicAdd(&nsel, 1); list[p] = i; }
                ++r;
            }
        }
        __syncthreads();
    }

    const int ns = nsel;
    if (tid < ns) {
        const int idx = list[tid];
        const float score = __uint_as_float(sv[idx]);
        const int ys = idx / W3C, xs = idx % W3C;
        const float d = depth[(size_t)b * NPIX + idx];
        const float u = ((float)xs + 0.5f) * 8.0f;
        const float v = ((float)ys + 0.5f) * 8.0f;
        const float* P = camP + b * 12;
        const float fx = fmaxf(P[0], 1e-4f), fy = fmaxf(P[5], 1e-4f);
        const float cx = P[2], cy = P[6], tx = P[3], ty = P[7];
        const float x_cam = (u * d - cx * d - tx) / fx;
        const float y_cam = (v * d - cy * d - ty) / fy;
        const float* T = camT + b * 16;
        const float lx = T[0] * x_cam + T[1] * y_cam + T[2] * d + T[3];
        const float ly = T[4] * x_cam + T[5] * y_cam + T[6] * d + T[7];
        const int gx = (int)floorf((lx - (-51.2f)) / 0.2f);
        const int gy = (int)floorf((ly - (-51.2f)) / 0.2f);
        if (gx >= 0 && gx < BEV && gy >= 0 && gy < BEV) {
            int* bb = (int*)(bev + (size_t)b * BEV * BEV);
#pragma unroll
            for (int dy = -2; dy <= 2; ++dy) {
                const int iy = gy + dy;
                if (iy < 0 || iy >= BEV) continue;
#pragma unroll
                for (int dx = -2; dx <= 2; ++dx) {
                    const int ix = gx + dx;
                    if (ix < 0 || ix >= BEV) continue;
                    const float g = expf((float)(-(dy * dy + dx * dx)) / 1.3888888888888890f);
                    atomicMax(&bb[iy * BEV + ix], __float_as_int(score * g));
                }
            }
        }
    }
}

// ---------------- clip + logit ----------------
__global__ void bev_finish(const float* __restrict__ bev, float* __restrict__ out_logits,
                           float* __restrict__ out_prob) {
    int i = blockIdx.x * blockDim.x + threadIdx.x;
    if (i >= BB * BEV * BEV) return;
    float p = bev[i];
    p = fminf(fmaxf(p, 1e-4f), 0.9999f);
    out_logits[i] = logf(p) - log1pf(-p);
    out_prob[i] = p;
}

// ---------------- launcher ----------------
extern "C" void kernel_launch(void* const* d_in, const int* in_sizes, int n_in,
                              void* d_out, int out_size, void* d_ws, size_t ws_size,
                              hipStream_t stream) {
    (void)in_sizes; (void)n_in; (void)out_size; (void)ws_size;
    const float* image = (const float*)d_in[0];
    const float* camP  = (const float*)d_in[1];
    const float* camT  = (const float*)d_in[2];
    const float* W1  = (const float*)d_in[3];
    const float* g1  = (const float*)d_in[4];
    const float* b1  = (const float*)d_in[5];
    const float* W2  = (const float*)d_in[6];
    const float* g2  = (const float*)d_in[7];
    const float* b2  = (const float*)d_in[8];
    const float* W3  = (const float*)d_in[9];
    const float* g3  = (const float*)d_in[10];
    const float* b3  = (const float*)d_in[11];
    const float* Wh1 = (const float*)d_in[12];
    const float* gh1 = (const float*)d_in[13];
    const float* bh1 = (const float*)d_in[14];
    const float* Wh2 = (const float*)d_in[15];
    const float* bh2 = (const float*)d_in[16];
    const float* Wd1 = (const float*)d_in[17];
    const float* gd1 = (const float*)d_in[18];
    const float* bd1 = (const float*)d_in[19];
    const float* Wd2 = (const float*)d_in[20];
    const float* bd2 = (const float*)d_in[21];

    float* ws = (float*)d_ws;
    float* x1    = ws + OFF_X1;
    float* x2    = ws + OFF_X2;
    float* feats = ws + OFF_F;
    float* prob  = ws + OFF_PROB;
    float* depw  = ws + OFF_DEP;
    float* hma   = ws + OFF_HMA;
    float* dla   = ws + OFF_DLA;
    float* bev   = ws + OFF_BEV;

    float* out       = (float*)d_out;
    float* out_hm    = out;                                // [4,1,64,176]
    float* out_depth = out + (size_t)BB * NPIX;            // [4,1,64,176]
    float* out_lg    = out + (size_t)2 * BB * NPIX;        // [4,1,512,512]
    float* out_pr    = out_lg + (size_t)BB * BEV * BEV;    // [4,1,512,512]

    const int TPB = 256;
    // zero bev + head accumulators first (ws is poisoned before every launch)
    zero_init<<<(BB * BEV * BEV + TPB - 1) / TPB, TPB, 0, stream>>>(bev, hma, dla);

    // conv1: 3 -> 32, s2 (single cin chunk)
    conv3x3_tiled<3, 2, 32, 3, 0, 1><<<dim3(11, H1C, BB), 256, 0, stream>>>(
        image, W1, g1, b1, x1, nullptr, IMG_H, IMG_W, H1C, W1C);
    // conv2: 32 -> 64, s2
    conv3x3_tiled<32, 2, 64, 8, 0, 1><<<dim3(6, H2C, BB), 256, 0, stream>>>(
        x1, W2, g2, b2, x2, nullptr, H1C, W1C, H2C, W2C);
    // conv3: 64 -> 96, s2, oc-split x2 for occupancy
    conv3x3_tiled<64, 2, 96, 8, 0, 2><<<dim3(3 * 2, H3C, BB), 256, 0, stream>>>(
        x2, W3, g3, b3, feats, nullptr, H2C, W2C, H3C, W3C);
    // heatmap head: 96 -> 96 (s1) -> 1x1 partial -> atomicAdd(hma)
    conv3x3_tiled<96, 1, 96, 8, 1, 2><<<dim3(3 * 2, H3C, BB), 256, 0, stream>>>(
        feats, Wh1, gh1, bh1, hma, Wh2, H3C, W3C, H3C, W3C);
    // depth head: 96 -> 96 (s1) -> 1x1 partial -> atomicAdd(dla)
    conv3x3_tiled<96, 1, 96, 8, 1, 2><<<dim3(3 * 2, H3C, BB), 256, 0, stream>>>(
        feats, Wd1, gd1, bd1, dla, Wd2, H3C, W3C, H3C, W3C);
    // bias + sigmoid/depth transforms
    heads_finish<<<(BB * NPIX + TPB - 1) / TPB, TPB, 0, stream>>>(
        hma, dla, bh2, bd2, out_hm, out_depth, prob, depw);

    // BEV: select+splat -> finish
    select_splat<<<BB, 1024, 0, stream>>>(prob, depw, camP, camT, bev);
    bev_finish<<<(BB * BEV * BEV + TPB - 1) / TPB, TPB, 0, stream>>>(bev, out_lg, out_pr);
}